// Round 5
// baseline (89.848 us; speedup 1.0000x reference)
//
#include <hip/hip_runtime.h>

#define QUERY 16
#define LATENT 64

typedef float f4 __attribute__((ext_vector_type(4)));

// Workspace layout (floats):
//   Cxy  @ 0      : [16][32][32] = 16384
//   Cxz  @ 16384  : [16][32][16] =  8192
//   Cyz  @ 24576  : [16][32][16] =  8192
//   Ctx  @ 32768  : [16][ 8][32] =  4096
//   Cty  @ 36864  : [16][ 8][32] =  4096
//   Ctz  @ 40960  : [16][ 8][16] =  2048

// ---------------------------------------------------------------------------
// Conv: one block = (plane, oc-pair, row-chunk). TWO stages of 32 ic each.
// IDENTICAL to round 4 — this round launches it twice as a timing probe:
// c = dur_new - dur_R4 (idempotent: rewrites the same ws values).
// ---------------------------------------------------------------------------
template<int H, int Wd, int CH, int WSOFF>
__device__ __forceinline__ void conv_block(
    const float* __restrict__ in, const float* __restrict__ Wt,
    const float* __restrict__ bias, float* __restrict__ ws,
    float* __restrict__ smem, int plane, int oc0, int chunk)
{
    constexpr int PW   = Wd + 2;
    constexpr int SLAB = (CH + 2) * PW;
    constexpr int TOT  = 32 * SLAB;       // floats staged per stage
    constexpr int NPX  = CH * Wd;
    constexpr int HW   = H * Wd;
    constexpr int LOGW = (Wd == 32) ? 5 : 4;

    const int tid = threadIdx.x;
    const int r   = (tid & (NPX - 1)) >> LOGW;
    const int c   = tid & (Wd - 1);

    const float* __restrict__ w0 = Wt + (size_t)((plane * QUERY + oc0) * LATENT) * 9;
    const float* __restrict__ w1 = w0 + LATENT * 9;

    float a0 = 0.f, a1 = 0.f, a2 = 0.f;
    float b0 = 0.f, b1 = 0.f, b2 = 0.f;

    #pragma unroll
    for (int half = 0; half < 2; ++half) {
        const float* __restrict__ src = in + half * 32 * HW;
        for (int s = tid; s < TOT; s += 256) {
            const int ic  = s / SLAB;
            const int rem = s - ic * SLAB;
            const int rr  = rem / PW;
            const int cc  = rem - rr * PW;
            const int row = chunk * CH + rr - 1;
            const int col = cc - 1;
            float v = 0.0f;
            if ((unsigned)row < (unsigned)H && (unsigned)col < (unsigned)Wd)
                v = src[ic * HW + row * Wd + col];
            smem[s] = v;
        }
        __syncthreads();

        if (tid < NPX) {
            const float* base = smem + (r + 1) * PW + (c + 1);
            const float* wa0  = w0 + half * 32 * 9;
            const float* wb0  = w1 + half * 32 * 9;
            #pragma unroll 4
            for (int il = 0; il < 32; ++il) {
                const float* bp = base + il * SLAB;
                const float t0 = bp[-PW - 1], t1 = bp[-PW], t2 = bp[-PW + 1];
                const float t3 = bp[-1],      t4 = bp[0],   t5 = bp[1];
                const float t6 = bp[PW - 1],  t7 = bp[PW],  t8 = bp[PW + 1];
                const float* wa = wa0 + il * 9;
                const float* wb = wb0 + il * 9;
                a0 += t0 * wa[0] + t1 * wa[1] + t2 * wa[2];
                a1 += t3 * wa[3] + t4 * wa[4] + t5 * wa[5];
                a2 += t6 * wa[6] + t7 * wa[7] + t8 * wa[8];
                b0 += t0 * wb[0] + t1 * wb[1] + t2 * wb[2];
                b1 += t3 * wb[3] + t4 * wb[4] + t5 * wb[5];
                b2 += t6 * wb[6] + t7 * wb[7] + t8 * wb[8];
            }
        }
        __syncthreads();
    }

    if (tid < NPX) {
        const float bias0 = bias[plane * QUERY + oc0];
        const float bias1 = bias[plane * QUERY + oc0 + 1];
        const float r0 = (a0 + a1) + (a2 + bias0);
        const float r1 = (b0 + b1) + (b2 + bias1);
        ws[WSOFF + (oc0    ) * HW + chunk * NPX + (tid & (NPX - 1))] = fmaxf(r0, 0.0f);
        ws[WSOFF + (oc0 + 1) * HW + chunk * NPX + (tid & (NPX - 1))] = fmaxf(r1, 0.0f);
    }
}

// Block map (88 blocks):
//  [ 0,32): xy  H=32 W=32 CH=8   (ocp = l>>2, chunk = l&3)
//  [32,48): xz  H=32 W=16 CH=16  (ocp = l>>1, chunk = l&1)
//  [48,64): yz  H=32 W=16 CH=16
//  [64,72): tx  H= 8 W=32 CH=8
//  [72,80): ty  H= 8 W=32 CH=8
//  [80,88): tz  H= 8 W=16 CH=8   (128 active px)
__global__ __launch_bounds__(256) void conv_relu_kernel(
    const float* __restrict__ p0, const float* __restrict__ p1,
    const float* __restrict__ p2, const float* __restrict__ p3,
    const float* __restrict__ p4, const float* __restrict__ p5,
    const float* __restrict__ Wt, const float* __restrict__ bias,
    float* __restrict__ ws)
{
    __shared__ float smem[10880];   // 32 ic * max slab 340 = 43.5 KB
    const int blk = blockIdx.x;

    if (blk < 32) {
        const int l = blk;
        conv_block<32, 32, 8, 0>(p0, Wt, bias, ws, smem, 0, (l >> 2) << 1, l & 3);
    } else if (blk < 48) {
        const int l = blk - 32;
        conv_block<32, 16, 16, 16384>(p1, Wt, bias, ws, smem, 1, (l >> 1) << 1, l & 1);
    } else if (blk < 64) {
        const int l = blk - 48;
        conv_block<32, 16, 16, 24576>(p2, Wt, bias, ws, smem, 2, (l >> 1) << 1, l & 1);
    } else if (blk < 72) {
        const int l = blk - 64;
        conv_block<8, 32, 8, 32768>(p3, Wt, bias, ws, smem, 3, l << 1, 0);
    } else if (blk < 80) {
        const int l = blk - 72;
        conv_block<8, 32, 8, 36864>(p4, Wt, bias, ws, smem, 4, l << 1, 0);
    } else {
        const int l = blk - 80;
        conv_block<8, 16, 8, 40960>(p5, Wt, bias, ws, smem, 5, l << 1, 0);
    }
}

// ---------------------------------------------------------------------------
// Voxel: one block per (x2,t2) -> 256 blocks, F built ONCE per block.
// IDENTICAL to round 4.
// out flat: (((t*64 + x)*64 + y)*32 + z)*16 + q
// ---------------------------------------------------------------------------
__global__ __launch_bounds__(512) void voxel_kernel(
    const float* __restrict__ ws, float* __restrict__ out)
{
    __shared__ float F[8192];   // [y2=32][z2=16][q=16]
    __shared__ float G[512];    // [y2=32][q=16]  Cxy*Cty
    __shared__ float Hh[256];   // [z2=16][q=16]  Cxz*Ctz*Ctx

    const int b   = blockIdx.x;     // 0..255
    const int x2  = b & 31;
    const int t2  = b >> 5;         // 0..7
    const int tid = threadIdx.x;    // 0..511

    const float* Cxy = ws;             // [16][32][32]
    const float* Cxz = ws + 16384;     // [16][32][16]
    const float* Cyz = ws + 24576;     // [16][32][16]
    const float* Ctx = ws + 32768;     // [16][ 8][32]
    const float* Cty = ws + 36864;     // [16][ 8][32]
    const float* Ctz = ws + 40960;     // [16][ 8][16]

    {
        const int y2 = tid >> 4, q = tid & 15;
        G[tid] = Cxy[q * 1024 + x2 * 32 + y2] * Cty[q * 256 + t2 * 32 + y2];
    }
    if (tid < 256) {
        const int z2 = tid >> 4, q = tid & 15;
        Hh[tid] = Cxz[q * 512 + x2 * 16 + z2]
                * Ctz[q * 128 + t2 * 16 + z2]
                * Ctx[q * 256 + t2 * 32 + x2];
    }
    __syncthreads();

    #pragma unroll
    for (int e = tid; e < 8192; e += 512) {
        const int q  = e & 15;
        const int z2 = (e >> 4) & 15;
        const int y2 = e >> 8;
        F[e] = G[(y2 << 4) | q] * Hh[(z2 << 4) | q]
             * Cyz[q * 512 + (y2 << 4) + z2];
    }
    __syncthreads();

    const int j0 = (tid & 3) << 2;
    const int z  = (tid >> 2) & 31;
    const int yh = (tid >> 7) & 1;
    const int xl = (tid >> 8) & 1;
    const int x  = (x2 << 1) | xl;
    const int t0_ = (t2 << 1);

    float* ob0 = out + ((((size_t)(t0_ * 64 + x)) * 64 + yh) * 32 + z) * 16 + j0;
    float* ob1 = ob0 + (size_t)64 * 64 * 32 * 16;   // t+1
    const float* Fb = F + ((z >> 1) << 4) + j0;

    #pragma unroll 8
    for (int y2 = 0; y2 < 32; ++y2) {
        const f4 v = *reinterpret_cast<const f4*>(Fb + (y2 << 8));
        __builtin_nontemporal_store(v, reinterpret_cast<f4*>(ob0 + (size_t)y2 * 1024));
        __builtin_nontemporal_store(v, reinterpret_cast<f4*>(ob1 + (size_t)y2 * 1024));
    }
}

extern "C" void kernel_launch(void* const* d_in, const int* in_sizes, int n_in,
                              void* d_out, int out_size, void* d_ws, size_t ws_size,
                              hipStream_t stream)
{
    const float* p_xy = (const float*)d_in[0];
    const float* p_xz = (const float*)d_in[1];
    const float* p_yz = (const float*)d_in[2];
    const float* p_tx = (const float*)d_in[3];
    const float* p_ty = (const float*)d_in[4];
    const float* p_tz = (const float*)d_in[5];
    const float* Wt   = (const float*)d_in[6];
    const float* bias = (const float*)d_in[7];

    float* ws  = (float*)d_ws;
    float* out = (float*)d_out;

    // DIAGNOSTIC: conv launched twice (idempotent). conv_cost = dur - 62.5us.
    conv_relu_kernel<<<88, 256, 0, stream>>>(p_xy, p_xz, p_yz, p_tx, p_ty, p_tz,
                                             Wt, bias, ws);
    conv_relu_kernel<<<88, 256, 0, stream>>>(p_xy, p_xz, p_yz, p_tx, p_ty, p_tz,
                                             Wt, bias, ws);
    voxel_kernel<<<256, 512, 0, stream>>>(ws, out);
}

// Round 6
// 53.384 us; speedup vs baseline: 1.6831x; 1.6831x over previous
//
#include <hip/hip_runtime.h>

#define QUERY 16
#define LATENT 64

typedef float f4 __attribute__((ext_vector_type(4)));

// Workspace layout (floats):
//   Cxy  @ 0      : [16][32][32] = 16384
//   Cxz  @ 16384  : [16][32][16] =  8192
//   Cyz  @ 24576  : [16][32][16] =  8192
//   Ctx  @ 32768  : [16][ 8][32] =  4096
//   Cty  @ 36864  : [16][ 8][32] =  4096
//   Ctz  @ 40960  : [16][ 8][16] =  2048

// ---------------------------------------------------------------------------
// Conv: one block = (plane, oc-pair, row-chunk). Two stages of 32 ic.
// Staging: one-time LDS zero-fill (halos stay zero), then interior copied
// with coalesced float4 loads + 16B-aligned ds_write_b128 (rows padded to
// PW = Wd+8, interior starts at col 4). Compute: 9 b32 taps + FMA with
// scalar-loaded (block-uniform) weights.
// ---------------------------------------------------------------------------
template<int H, int Wd, int CH, int WSOFF>
__device__ __forceinline__ void conv_block(
    const float* __restrict__ in, const float* __restrict__ Wt,
    const float* __restrict__ bias, float* __restrict__ ws,
    float* __restrict__ smem, int plane, int oc0, int chunk)
{
    constexpr int PW    = Wd + 8;            // 4-col pad left/right: aligned rows
    constexpr int ROWS  = CH + 2;
    constexpr int SLAB  = ROWS * PW;
    constexpr int HALF  = 32;                // ic per stage
    constexpr int NPX   = CH * Wd;
    constexpr int HW    = H * Wd;
    constexpr int LOGW  = (Wd == 32) ? 5 : 4;
    constexpr int RF4   = Wd / 4;            // f4 per interior row
    constexpr int TOTF4 = HALF * ROWS * RF4; // f4 copied per stage
    constexpr int NF4   = HALF * SLAB / 4;   // f4 in buffer

    const int tid = threadIdx.x;

    // one-time zero fill: halo cells never overwritten, stay zero both halves
    {
        const f4 zz = {0.f, 0.f, 0.f, 0.f};
        for (int i = tid; i < NF4; i += 256)
            reinterpret_cast<f4*>(smem)[i] = zz;
    }
    __syncthreads();

    const int r = (tid & (NPX - 1)) >> LOGW;
    const int c = tid & (Wd - 1);

    const float* __restrict__ w0 = Wt + (size_t)((plane * QUERY + oc0) * LATENT) * 9;
    const float* __restrict__ w1 = w0 + LATENT * 9;

    float a0 = 0.f, a1 = 0.f, a2 = 0.f;
    float b0 = 0.f, b1 = 0.f, b2 = 0.f;

    #pragma unroll
    for (int half = 0; half < 2; ++half) {
        const float* __restrict__ src = in + half * HALF * HW;

        // interior copy: batched f4 loads (independent) -> aligned b128 writes
        #pragma unroll
        for (int s = tid; s < TOTF4; s += 256) {
            const int il  = s / (ROWS * RF4);
            const int rem = s - il * (ROWS * RF4);
            const int r2  = rem / RF4;
            const int c4  = rem - r2 * RF4;
            const int gr  = chunk * CH + r2 - 1;
            if ((unsigned)gr < (unsigned)H) {
                const f4 v = *reinterpret_cast<const f4*>(
                    src + il * HW + gr * Wd + (c4 << 2));
                *reinterpret_cast<f4*>(
                    smem + il * SLAB + r2 * PW + 4 + (c4 << 2)) = v;
            }
        }
        __syncthreads();

        if (tid < NPX) {
            const float* base = smem + (r + 1) * PW + (c + 4);
            const float* wa0  = w0 + half * HALF * 9;
            const float* wb0  = w1 + half * HALF * 9;
            #pragma unroll 8
            for (int il = 0; il < HALF; ++il) {
                const float* bp = base + il * SLAB;
                const float t0 = bp[-PW - 1], t1 = bp[-PW], t2 = bp[-PW + 1];
                const float t3 = bp[-1],      t4 = bp[0],   t5 = bp[1];
                const float t6 = bp[PW - 1],  t7 = bp[PW],  t8 = bp[PW + 1];
                const float* wa = wa0 + il * 9;
                const float* wb = wb0 + il * 9;
                a0 += t0 * wa[0] + t1 * wa[1] + t2 * wa[2];
                a1 += t3 * wa[3] + t4 * wa[4] + t5 * wa[5];
                a2 += t6 * wa[6] + t7 * wa[7] + t8 * wa[8];
                b0 += t0 * wb[0] + t1 * wb[1] + t2 * wb[2];
                b1 += t3 * wb[3] + t4 * wb[4] + t5 * wb[5];
                b2 += t6 * wb[6] + t7 * wb[7] + t8 * wb[8];
            }
        }
        __syncthreads();
    }

    if (tid < NPX) {
        const float bias0 = bias[plane * QUERY + oc0];
        const float bias1 = bias[plane * QUERY + oc0 + 1];
        const float r0 = (a0 + a1) + (a2 + bias0);
        const float r1 = (b0 + b1) + (b2 + bias1);
        const int   px = tid & (NPX - 1);
        ws[WSOFF + (oc0    ) * HW + chunk * NPX + px] = fmaxf(r0, 0.0f);
        ws[WSOFF + (oc0 + 1) * HW + chunk * NPX + px] = fmaxf(r1, 0.0f);
    }
}

// Block map (88 blocks):
//  [ 0,32): xy  H=32 W=32 CH=8   (ocp = l>>2, chunk = l&3)
//  [32,48): xz  H=32 W=16 CH=16  (ocp = l>>1, chunk = l&1)
//  [48,64): yz  H=32 W=16 CH=16
//  [64,72): tx  H= 8 W=32 CH=8
//  [72,80): ty  H= 8 W=32 CH=8
//  [80,88): tz  H= 8 W=16 CH=8   (128 active px)
__global__ __launch_bounds__(256) void conv_relu_kernel(
    const float* __restrict__ p0, const float* __restrict__ p1,
    const float* __restrict__ p2, const float* __restrict__ p3,
    const float* __restrict__ p4, const float* __restrict__ p5,
    const float* __restrict__ Wt, const float* __restrict__ bias,
    float* __restrict__ ws)
{
    __shared__ float smem[13824];   // max: 32 ic * 18*24 = 55.3 KB (xz/yz)
    const int blk = blockIdx.x;

    if (blk < 32) {
        const int l = blk;
        conv_block<32, 32, 8, 0>(p0, Wt, bias, ws, smem, 0, (l >> 2) << 1, l & 3);
    } else if (blk < 48) {
        const int l = blk - 32;
        conv_block<32, 16, 16, 16384>(p1, Wt, bias, ws, smem, 1, (l >> 1) << 1, l & 1);
    } else if (blk < 64) {
        const int l = blk - 48;
        conv_block<32, 16, 16, 24576>(p2, Wt, bias, ws, smem, 2, (l >> 1) << 1, l & 1);
    } else if (blk < 72) {
        const int l = blk - 64;
        conv_block<8, 32, 8, 32768>(p3, Wt, bias, ws, smem, 3, l << 1, 0);
    } else if (blk < 80) {
        const int l = blk - 72;
        conv_block<8, 32, 8, 36864>(p4, Wt, bias, ws, smem, 4, l << 1, 0);
    } else {
        const int l = blk - 80;
        conv_block<8, 16, 8, 40960>(p5, Wt, bias, ws, smem, 5, l << 1, 0);
    }
}

// ---------------------------------------------------------------------------
// Voxel: one block per (x2, t2, y2-half) -> 512 blocks (2/CU).
// F built once per block (local 16 y2 values); write loop: 1 ds_read_b128
// feeds 2 cached dwordx4 stores (t = 2*t2, 2*t2+1). No nt: the 134 MB output
// fits in the 256 MiB L3 -> let the cache hierarchy absorb the write stream.
// out flat: (((t*64 + x)*64 + y)*32 + z)*16 + q
// ---------------------------------------------------------------------------
__global__ __launch_bounds__(512) void voxel_kernel(
    const float* __restrict__ ws, float* __restrict__ out)
{
    __shared__ float F[4096];   // [y2l=16][z2=16][q=16]
    __shared__ float G[256];    // [y2l=16][q=16]  Cxy*Cty
    __shared__ float Hh[256];   // [z2=16][q=16]   Cxz*Ctz*Ctx

    const int b   = blockIdx.x;     // 0..511
    const int x2  = b & 31;
    const int t2  = (b >> 5) & 7;
    const int yh2 = b >> 8;         // y2 half: 0/1
    const int tid = threadIdx.x;    // 0..511

    const float* Cxy = ws;             // [16][32][32]
    const float* Cxz = ws + 16384;     // [16][32][16]
    const float* Cyz = ws + 24576;     // [16][32][16]
    const float* Ctx = ws + 32768;     // [16][ 8][32]
    const float* Cty = ws + 36864;     // [16][ 8][32]
    const float* Ctz = ws + 40960;     // [16][ 8][16]

    if (tid < 256) {
        const int y2l = tid >> 4, q = tid & 15;
        const int y2  = yh2 * 16 + y2l;
        G[tid] = Cxy[q * 1024 + x2 * 32 + y2] * Cty[q * 256 + t2 * 32 + y2];
    } else {
        const int i  = tid - 256;
        const int z2 = i >> 4, q = i & 15;
        Hh[i] = Cxz[q * 512 + x2 * 16 + z2]
              * Ctz[q * 128 + t2 * 16 + z2]
              * Ctx[q * 256 + t2 * 32 + x2];
    }
    __syncthreads();

    #pragma unroll
    for (int e = tid; e < 4096; e += 512) {
        const int q   = e & 15;
        const int z2  = (e >> 4) & 15;
        const int y2l = e >> 8;
        const int y2  = yh2 * 16 + y2l;
        F[e] = G[(y2l << 4) | q] * Hh[(z2 << 4) | q]
             * Cyz[q * 512 + (y2 << 4) + z2];
    }
    __syncthreads();

    const int j0  = (tid & 3) << 2;
    const int z   = (tid >> 2) & 31;
    const int yhp = (tid >> 7) & 1;   // y parity
    const int xl  = (tid >> 8) & 1;
    const int x   = (x2 << 1) | xl;
    const int t0_ = t2 << 1;
    const int y0  = yh2 * 32 + yhp;

    float* ob0 = out + ((((size_t)(t0_ * 64 + x)) * 64 + y0) * 32 + z) * 16 + j0;
    float* ob1 = ob0 + (size_t)64 * 64 * 32 * 16;   // t+1
    const float* Fb = F + ((z >> 1) << 4) + j0;

    #pragma unroll
    for (int y2l = 0; y2l < 16; ++y2l) {
        const f4 v = *reinterpret_cast<const f4*>(Fb + (y2l << 8));
        *reinterpret_cast<f4*>(ob0 + (size_t)y2l * 1024) = v;
        *reinterpret_cast<f4*>(ob1 + (size_t)y2l * 1024) = v;
    }
}

extern "C" void kernel_launch(void* const* d_in, const int* in_sizes, int n_in,
                              void* d_out, int out_size, void* d_ws, size_t ws_size,
                              hipStream_t stream)
{
    const float* p_xy = (const float*)d_in[0];
    const float* p_xz = (const float*)d_in[1];
    const float* p_yz = (const float*)d_in[2];
    const float* p_tx = (const float*)d_in[3];
    const float* p_ty = (const float*)d_in[4];
    const float* p_tz = (const float*)d_in[5];
    const float* Wt   = (const float*)d_in[6];
    const float* bias = (const float*)d_in[7];

    float* ws  = (float*)d_ws;
    float* out = (float*)d_out;

    conv_relu_kernel<<<88, 256, 0, stream>>>(p_xy, p_xz, p_yz, p_tx, p_ty, p_tz,
                                             Wt, bias, ws);
    voxel_kernel<<<512, 512, 0, stream>>>(ws, out);
}